// Round 2
// baseline (2305.599 us; speedup 1.0000x reference)
//
#include <hip/hip_runtime.h>

namespace {

constexpr int T_LEN = 512;
constexpr int IN_D  = 16;
constexpr int TC    = 16;   // timesteps staged per x-chunk
constexpr int NB    = 2;    // batch elements per lane

__device__ __forceinline__ float fast_sigmoid(float x) {
    return __builtin_amdgcn_rcpf(1.0f + __expf(-x));
}
__device__ __forceinline__ float fast_tanh(float x) {
    // 2*sigmoid(2x)-1 : saturates cleanly to +/-1, no NaN at |x| large
    return 2.0f * __builtin_amdgcn_rcpf(1.0f + __expf(-2.0f * x)) - 1.0f;
}

// block = 256 threads = 4 waves (64 lanes each); wave = 2 groups x 32 lanes;
// lane owns hidden unit j for NB=2 batch elements -> 4 batch/wave, 16/block.
__global__ __launch_bounds__(256)
void lstm2_head_kernel(const float* __restrict__ x,
                       const float* __restrict__ Wih0, const float* __restrict__ Whh0,
                       const float* __restrict__ bih0, const float* __restrict__ bhh0,
                       const float* __restrict__ Wih1, const float* __restrict__ Whh1,
                       const float* __restrict__ bih1, const float* __restrict__ bhh1,
                       const float* __restrict__ W1, const float* __restrict__ b1,
                       const float* __restrict__ W2, const float* __restrict__ b2,
                       float* __restrict__ out)
{
    // gate-packed weights: s[k*32+j] = {W[0*32+j][k], W[32+j][k], W[64+j][k], W[96+j][k]}
    __shared__ float4 wih0s[16 * 32];
    __shared__ float4 whh0s[32 * 32];
    __shared__ float4 wih1s[32 * 32];
    __shared__ float4 whh1s[32 * 32];
    __shared__ float4 xs[4][4][TC * 4];     // [wave][batch_in_wave][tt*4+kq]
    __shared__ float4 hb[4][2][NB][2][8];   // [wave][grp][n][layer][kq] : h exchange

    const int tid = threadIdx.x;

    // ---- stage weights into LDS (once) ----
    for (int i = tid; i < 16 * 32; i += 256) {
        const int k = i >> 5, j = i & 31;
        wih0s[i] = make_float4(Wih0[(     j) * 16 + k], Wih0[(32 + j) * 16 + k],
                               Wih0[(64 + j) * 16 + k], Wih0[(96 + j) * 16 + k]);
    }
    for (int i = tid; i < 32 * 32; i += 256) {
        const int k = i >> 5, j = i & 31;
        whh0s[i] = make_float4(Whh0[(     j) * 32 + k], Whh0[(32 + j) * 32 + k],
                               Whh0[(64 + j) * 32 + k], Whh0[(96 + j) * 32 + k]);
        wih1s[i] = make_float4(Wih1[(     j) * 32 + k], Wih1[(32 + j) * 32 + k],
                               Wih1[(64 + j) * 32 + k], Wih1[(96 + j) * 32 + k]);
        whh1s[i] = make_float4(Whh1[(     j) * 32 + k], Whh1[(32 + j) * 32 + k],
                               Whh1[(64 + j) * 32 + k], Whh1[(96 + j) * 32 + k]);
    }
    __syncthreads();

    const int wave = tid >> 6;                     // 0..3
    const int lane = tid & 63;
    const int grp  = lane >> 5;
    const int j    = lane & 31;
    const int bw   = blockIdx.x * 16 + wave * 4;   // first batch of this wave
    const int bb   = bw + grp * NB;                // first batch of this (wave,grp)

    float bs0[4], bs1[4];
    #pragma unroll
    for (int g = 0; g < 4; ++g) {
        bs0[g] = bih0[g * 32 + j] + bhh0[g * 32 + j];
        bs1[g] = bih1[g * 32 + j] + bhh1[g * 32 + j];
    }

    float c1[NB] = {0.f, 0.f}, c2[NB] = {0.f, 0.f};
    #pragma unroll
    for (int n = 0; n < NB; ++n) {
        ((float*)&hb[wave][grp][n][0][0])[j] = 0.f;   // h1_{-1}=0
        ((float*)&hb[wave][grp][n][1][0])[j] = 0.f;   // h2_{-1}=0
    }

    #pragma unroll 1
    for (int t0 = 0; t0 < T_LEN; t0 += TC) {
        {   // stage x chunk for this wave's 4 batch rows (coalesced float4)
            const int bl = lane >> 4, part = lane & 15;
            const float4* xg = (const float4*)x +
                ((size_t)(bw + bl) * (T_LEN * IN_D) + (size_t)t0 * IN_D) / 4;
            #pragma unroll
            for (int ii = 0; ii < 4; ++ii)
                xs[wave][bl][ii * 16 + part] = xg[ii * 16 + part];
        }

        #pragma unroll 1
        for (int tt = 0; tt < TC; ++tt) {
            float a[NB][4];

            // ================= layer 1 =================
            #pragma unroll
            for (int n = 0; n < NB; ++n)
                #pragma unroll
                for (int g = 0; g < 4; ++g) a[n][g] = bs0[g];

            // input contribution: k = 0..15
            #pragma unroll
            for (int kq = 0; kq < 4; ++kq) {
                const float4 v0 = xs[wave][grp * NB + 0][tt * 4 + kq];
                const float4 v1 = xs[wave][grp * NB + 1][tt * 4 + kq];
                #pragma unroll
                for (int kk = 0; kk < 4; ++kk) {
                    const float4 w = wih0s[(kq * 4 + kk) * 32 + j];
                    const float e0 = ((const float*)&v0)[kk];
                    const float e1 = ((const float*)&v1)[kk];
                    a[0][0] += w.x * e0; a[0][1] += w.y * e0; a[0][2] += w.z * e0; a[0][3] += w.w * e0;
                    a[1][0] += w.x * e1; a[1][1] += w.y * e1; a[1][2] += w.z * e1; a[1][3] += w.w * e1;
                }
            }
            // recurrent contribution: h1_{t-1}
            #pragma unroll
            for (int kq = 0; kq < 8; ++kq) {
                const float4 v0 = hb[wave][grp][0][0][kq];
                const float4 v1 = hb[wave][grp][1][0][kq];
                #pragma unroll
                for (int kk = 0; kk < 4; ++kk) {
                    const float4 w = whh0s[(kq * 4 + kk) * 32 + j];
                    const float e0 = ((const float*)&v0)[kk];
                    const float e1 = ((const float*)&v1)[kk];
                    a[0][0] += w.x * e0; a[0][1] += w.y * e0; a[0][2] += w.z * e0; a[0][3] += w.w * e0;
                    a[1][0] += w.x * e1; a[1][1] += w.y * e1; a[1][2] += w.z * e1; a[1][3] += w.w * e1;
                }
            }
            #pragma unroll
            for (int n = 0; n < NB; ++n) {
                const float ig = fast_sigmoid(a[n][0]);
                const float fg = fast_sigmoid(a[n][1]);
                const float gg = fast_tanh(a[n][2]);
                const float og = fast_sigmoid(a[n][3]);
                c1[n] = fg * c1[n] + ig * gg;
                const float h1n = og * fast_tanh(c1[n]);
                ((float*)&hb[wave][grp][n][0][0])[j] = h1n;   // publish h1_t
            }

            // ================= layer 2 =================
            #pragma unroll
            for (int n = 0; n < NB; ++n)
                #pragma unroll
                for (int g = 0; g < 4; ++g) a[n][g] = bs1[g];

            // input contribution: h1_t (just published, same-wave in-order LDS)
            #pragma unroll
            for (int kq = 0; kq < 8; ++kq) {
                const float4 v0 = hb[wave][grp][0][0][kq];
                const float4 v1 = hb[wave][grp][1][0][kq];
                #pragma unroll
                for (int kk = 0; kk < 4; ++kk) {
                    const float4 w = wih1s[(kq * 4 + kk) * 32 + j];
                    const float e0 = ((const float*)&v0)[kk];
                    const float e1 = ((const float*)&v1)[kk];
                    a[0][0] += w.x * e0; a[0][1] += w.y * e0; a[0][2] += w.z * e0; a[0][3] += w.w * e0;
                    a[1][0] += w.x * e1; a[1][1] += w.y * e1; a[1][2] += w.z * e1; a[1][3] += w.w * e1;
                }
            }
            // recurrent contribution: h2_{t-1}
            #pragma unroll
            for (int kq = 0; kq < 8; ++kq) {
                const float4 v0 = hb[wave][grp][0][1][kq];
                const float4 v1 = hb[wave][grp][1][1][kq];
                #pragma unroll
                for (int kk = 0; kk < 4; ++kk) {
                    const float4 w = whh1s[(kq * 4 + kk) * 32 + j];
                    const float e0 = ((const float*)&v0)[kk];
                    const float e1 = ((const float*)&v1)[kk];
                    a[0][0] += w.x * e0; a[0][1] += w.y * e0; a[0][2] += w.z * e0; a[0][3] += w.w * e0;
                    a[1][0] += w.x * e1; a[1][1] += w.y * e1; a[1][2] += w.z * e1; a[1][3] += w.w * e1;
                }
            }
            #pragma unroll
            for (int n = 0; n < NB; ++n) {
                const float ig = fast_sigmoid(a[n][0]);
                const float fg = fast_sigmoid(a[n][1]);
                const float gg = fast_tanh(a[n][2]);
                const float og = fast_sigmoid(a[n][3]);
                c2[n] = fg * c2[n] + ig * gg;
                const float h2n = og * fast_tanh(c2[n]);
                ((float*)&hb[wave][grp][n][1][0])[j] = h2n;   // publish h2_t
            }
        }
    }

    // ================= MLP head on h2[:, -1, :] =================
    #pragma unroll
    for (int n = 0; n < NB; ++n) {
        float p = 0.f;
        if (j < 16) {
            float acc = b1[j];
            #pragma unroll
            for (int kq = 0; kq < 8; ++kq) {
                const float4 hv = hb[wave][grp][n][1][kq];
                acc += W1[j * 32 + kq * 4 + 0] * hv.x;
                acc += W1[j * 32 + kq * 4 + 1] * hv.y;
                acc += W1[j * 32 + kq * 4 + 2] * hv.z;
                acc += W1[j * 32 + kq * 4 + 3] * hv.w;
            }
            p = W2[j] * fmaxf(acc, 0.f);
        }
        #pragma unroll
        for (int off = 16; off >= 1; off >>= 1)
            p += __shfl_xor(p, off, 32);
        if (j == 0) out[bb + n] = p + b2[0];
    }
}

} // namespace

extern "C" void kernel_launch(void* const* d_in, const int* in_sizes, int n_in,
                              void* d_out, int out_size, void* d_ws, size_t ws_size,
                              hipStream_t stream) {
    const float* x    = (const float*)d_in[0];
    const float* Wih0 = (const float*)d_in[1];
    const float* Whh0 = (const float*)d_in[2];
    const float* bih0 = (const float*)d_in[3];
    const float* bhh0 = (const float*)d_in[4];
    const float* Wih1 = (const float*)d_in[5];
    const float* Whh1 = (const float*)d_in[6];
    const float* bih1 = (const float*)d_in[7];
    const float* bhh1 = (const float*)d_in[8];
    const float* W1   = (const float*)d_in[9];
    const float* b1   = (const float*)d_in[10];
    const float* W2   = (const float*)d_in[11];
    const float* b2   = (const float*)d_in[12];

    const int batch  = out_size;            // 4096
    const int blocks = (batch + 15) / 16;   // 16 batch elements per block

    hipLaunchKernelGGL(lstm2_head_kernel, dim3(blocks), dim3(256), 0, stream,
                       x, Wih0, Whh0, bih0, bhh0, Wih1, Whh1, bih1, bhh1,
                       W1, b1, W2, b2, (float*)d_out);
}

// Round 3
// 1505.173 us; speedup vs baseline: 1.5318x; 1.5318x over previous
//
#include <hip/hip_runtime.h>

namespace {

constexpr int T_LEN = 512;
constexpr int TC    = 16;   // timesteps staged per x-chunk

__device__ __forceinline__ float fsig(float x) {
    return __builtin_amdgcn_rcpf(1.0f + __expf(-x));
}
__device__ __forceinline__ float ftanh(float x) {
    return 2.0f * __builtin_amdgcn_rcpf(1.0f + __expf(-2.0f * x)) - 1.0f;
}

// 1 batch per wave (block = 64 threads). lane = (kh = lane>>5, j = lane&31):
// j = hidden unit, kh = k-half of every 32-long reduction.
// Whh0/Wih1/Whh1 quarters live in VGPRs (192 regs); Wih0 + x chunk in LDS.
// Target: <=256 VGPR -> 2 waves/SIMD (8 waves/CU).
__global__ __launch_bounds__(64, 2)
void lstm2_head_kernel(const float* __restrict__ x,
                       const float* __restrict__ Wih0, const float* __restrict__ Whh0,
                       const float* __restrict__ bih0, const float* __restrict__ bhh0,
                       const float* __restrict__ Wih1, const float* __restrict__ Whh1,
                       const float* __restrict__ bih1, const float* __restrict__ bhh1,
                       const float* __restrict__ W1, const float* __restrict__ b1,
                       const float* __restrict__ W2, const float* __restrict__ b2,
                       float* __restrict__ out)
{
    __shared__ float4 wih0s[16 * 32];   // [k][j] -> {gate i,f,g,o} packed
    __shared__ float4 xls[TC * 4];      // [t][k] : 16 x 16 floats
    __shared__ float4 hx1v[8];          // h1_t broadcast buffer (32 floats)
    __shared__ float4 hx2v[8];          // h2_t broadcast buffer
    float* const hx1 = (float*)hx1v;
    float* const hx2 = (float*)hx2v;

    const int lane = threadIdx.x;       // 0..63
    const int kh   = lane >> 5;         // k-half
    const int j    = lane & 31;         // hidden unit
    const int b    = blockIdx.x;        // batch element

    // ---- stage Wih0 gate-packed into LDS ----
    for (int i = lane; i < 16 * 32; i += 64) {
        const int k = i >> 5, jj = i & 31;
        wih0s[i] = make_float4(Wih0[(     jj) * 16 + k], Wih0[(32 + jj) * 16 + k],
                               Wih0[(64 + jj) * 16 + k], Wih0[(96 + jj) * 16 + k]);
    }
    if (lane < 32) { hx1[lane] = 0.f; hx2[lane] = 0.f; }

    // ---- per-lane persistent weight registers (192 VGPRs) ----
    float whh0r[4][16], wih1r[4][16], whh1r[4][16];
    #pragma unroll
    for (int g = 0; g < 4; ++g) {
        const int row = g * 32 + j;
        #pragma unroll
        for (int kk = 0; kk < 16; ++kk) {
            whh0r[g][kk] = Whh0[row * 32 + kh * 16 + kk];
            wih1r[g][kk] = Wih1[row * 32 + kh * 16 + kk];
            whh1r[g][kk] = Whh1[row * 32 + kh * 16 + kk];
        }
    }
    float bs0[4], bs1[4];
    #pragma unroll
    for (int g = 0; g < 4; ++g) {
        bs0[g] = bih0[g * 32 + j] + bhh0[g * 32 + j];
        bs1[g] = bih1[g * 32 + j] + bhh1[g * 32 + j];
    }

    float4 h1h[4];                      // h1[kh*16 .. kh*16+15]
    #pragma unroll
    for (int q = 0; q < 4; ++q) h1h[q] = make_float4(0.f, 0.f, 0.f, 0.f);
    float c1 = 0.f, c2 = 0.f;

    const float4* xg = (const float4*)(x + (size_t)b * T_LEN * 16);

    #pragma unroll 1
    for (int t0 = 0; t0 < T_LEN; t0 += TC) {
        __builtin_amdgcn_wave_barrier();
        xls[lane] = xg[(t0 * 16) / 4 + lane];   // coalesced 1 KiB chunk
        __builtin_amdgcn_wave_barrier();

        #pragma unroll 1
        for (int tt = 0; tt < TC; ++tt) {
            // ================= layer 1 =================
            float a0 = 0.f, a1 = 0.f, a2 = 0.f, a3 = 0.f;
            // x part: k in [kh*8, kh*8+8)
            #pragma unroll
            for (int kq = 0; kq < 2; ++kq) {
                const float4 xv = xls[tt * 4 + kh * 2 + kq];
                #pragma unroll
                for (int e = 0; e < 4; ++e) {
                    const float4 w4 = wih0s[(kh * 8 + kq * 4 + e) * 32 + j];
                    const float xe = ((const float*)&xv)[e];
                    a0 += w4.x * xe; a1 += w4.y * xe; a2 += w4.z * xe; a3 += w4.w * xe;
                }
            }
            // recurrent part: h1_{t-1}[kh-half] (registers)
            #pragma unroll
            for (int q = 0; q < 4; ++q) {
                #pragma unroll
                for (int e = 0; e < 4; ++e) {
                    const float hv = ((const float*)&h1h[q])[e];
                    const int kk = q * 4 + e;
                    a0 += whh0r[0][kk] * hv; a1 += whh0r[1][kk] * hv;
                    a2 += whh0r[2][kk] * hv; a3 += whh0r[3][kk] * hv;
                }
            }
            // combine k-halves (both halves end with the full sum)
            a0 += __shfl_xor(a0, 32, 64);
            a1 += __shfl_xor(a1, 32, 64);
            a2 += __shfl_xor(a2, 32, 64);
            a3 += __shfl_xor(a3, 32, 64);
            {
                const float ig = fsig(a0 + bs0[0]);
                const float fg = fsig(a1 + bs0[1]);
                const float gg = ftanh(a2 + bs0[2]);
                const float og = fsig(a3 + bs0[3]);
                c1 = fg * c1 + ig * gg;
                const float h1 = og * ftanh(c1);
                hx1[j] = h1;            // both kh halves write the same value
            }
            __builtin_amdgcn_wave_barrier();
            #pragma unroll
            for (int q = 0; q < 4; ++q) h1h[q] = hx1v[kh * 4 + q];  // reload h1_t

            // ================= layer 2 =================
            float p0 = 0.f, p1 = 0.f, p2 = 0.f, p3 = 0.f;
            // input part: h1_t[kh-half]
            #pragma unroll
            for (int q = 0; q < 4; ++q) {
                #pragma unroll
                for (int e = 0; e < 4; ++e) {
                    const float hv = ((const float*)&h1h[q])[e];
                    const int kk = q * 4 + e;
                    p0 += wih1r[0][kk] * hv; p1 += wih1r[1][kk] * hv;
                    p2 += wih1r[2][kk] * hv; p3 += wih1r[3][kk] * hv;
                }
            }
            // recurrent part: h2_{t-1}[kh-half] (read before this step's publish)
            #pragma unroll
            for (int q = 0; q < 4; ++q) {
                const float4 h2v = hx2v[kh * 4 + q];
                #pragma unroll
                for (int e = 0; e < 4; ++e) {
                    const float hv = ((const float*)&h2v)[e];
                    const int kk = q * 4 + e;
                    p0 += whh1r[0][kk] * hv; p1 += whh1r[1][kk] * hv;
                    p2 += whh1r[2][kk] * hv; p3 += whh1r[3][kk] * hv;
                }
            }
            p0 += __shfl_xor(p0, 32, 64);
            p1 += __shfl_xor(p1, 32, 64);
            p2 += __shfl_xor(p2, 32, 64);
            p3 += __shfl_xor(p3, 32, 64);
            {
                const float ig = fsig(p0 + bs1[0]);
                const float fg = fsig(p1 + bs1[1]);
                const float gg = ftanh(p2 + bs1[2]);
                const float og = fsig(p3 + bs1[3]);
                c2 = fg * c2 + ig * gg;
                const float h2 = og * ftanh(c2);
                hx2[j] = h2;
            }
            __builtin_amdgcn_wave_barrier();
        }
    }

    // ================= MLP head on h2_{T-1} =================
    float p = 0.f;
    if (lane < 16) {
        float acc = b1[lane];
        #pragma unroll
        for (int k = 0; k < 32; ++k) acc += W1[lane * 32 + k] * hx2[k];
        p = W2[lane] * fmaxf(acc, 0.f);
    }
    p += __shfl_xor(p, 8, 64);
    p += __shfl_xor(p, 4, 64);
    p += __shfl_xor(p, 2, 64);
    p += __shfl_xor(p, 1, 64);
    if (lane == 0) out[b] = p + b2[0];
}

} // namespace

extern "C" void kernel_launch(void* const* d_in, const int* in_sizes, int n_in,
                              void* d_out, int out_size, void* d_ws, size_t ws_size,
                              hipStream_t stream) {
    const float* x    = (const float*)d_in[0];
    const float* Wih0 = (const float*)d_in[1];
    const float* Whh0 = (const float*)d_in[2];
    const float* bih0 = (const float*)d_in[3];
    const float* bhh0 = (const float*)d_in[4];
    const float* Wih1 = (const float*)d_in[5];
    const float* Whh1 = (const float*)d_in[6];
    const float* bih1 = (const float*)d_in[7];
    const float* bhh1 = (const float*)d_in[8];
    const float* W1   = (const float*)d_in[9];
    const float* b1   = (const float*)d_in[10];
    const float* W2   = (const float*)d_in[11];
    const float* b2   = (const float*)d_in[12];

    const int batch = out_size;         // 4096 -> 4096 single-wave blocks

    hipLaunchKernelGGL(lstm2_head_kernel, dim3(batch), dim3(64), 0, stream,
                       x, Wih0, Whh0, bih0, bhh0, Wih1, Whh1, bih1, bhh1,
                       W1, b1, W2, b2, (float*)d_out);
}

// Round 4
// 1371.398 us; speedup vs baseline: 1.6812x; 1.0975x over previous
//
#include <hip/hip_runtime.h>

namespace {

typedef __attribute__((ext_vector_type(8))) short short8;   // 8 bf16 (4 VGPRs)
typedef __attribute__((ext_vector_type(4))) float f32x4;

constexpr int T_LEN = 512;
constexpr int TC    = 16;       // timesteps per x-staging chunk
constexpr int HS    = 36;       // hbuf row stride (32 + 4 pad: bank-spread, 16B-aligned)
constexpr int XS    = 260;      // xp batch stride in dwords (16B-aligned, bank-spread)

__device__ __forceinline__ float fsig(float x) {
    return __builtin_amdgcn_rcpf(1.0f + __expf(-x));
}
__device__ __forceinline__ float ftanh(float x) {
    return 2.0f * __builtin_amdgcn_rcpf(1.0f + __expf(-2.0f * x)) - 1.0f;
}
// pack float -> [bf16_hi | bf16_lo] in one dword (hi in top 16 bits)
__device__ __forceinline__ unsigned pack_hilo(float v) {
    unsigned b  = __float_as_uint(v);
    unsigned hi = b & 0xffff0000u;
    float  lof  = v - __uint_as_float(hi);
    return hi | (__float_as_uint(lof) >> 16);
}
__device__ __forceinline__ f32x4 mfma16(short8 a, short8 b, f32x4 c) {
    return __builtin_amdgcn_mfma_f32_16x16x32_bf16(a, b, c, 0, 0, 0);
}
// split 8 fp32 into hi/lo bf16 fragments
__device__ __forceinline__ void split8(const float* w, short8& hi8, short8& lo8) {
    #pragma unroll
    for (int e = 0; e < 8; ++e) {
        unsigned b = __float_as_uint(w[e]);
        hi8[e] = (short)(b >> 16);
        float hif = __uint_as_float(b & 0xffff0000u);
        lo8[e] = (short)(__float_as_uint(w[e] - hif) >> 16);
    }
}

union FragU { short8 s; unsigned u[4]; };

// build a_hi/a_lo fragments from 8 LDS dwords each packed [hi16|lo16]
__device__ __forceinline__ void frags_from_dwords(const unsigned* p, short8& ahi, short8& alo) {
    uint4 d0 = *(const uint4*)p;
    uint4 d1 = *(const uint4*)(p + 4);
    FragU H, L;
    // result low short = elem 2i (hi/lo half), high short = elem 2i+1
    H.u[0] = __builtin_amdgcn_perm(d0.y, d0.x, 0x07060302u);
    H.u[1] = __builtin_amdgcn_perm(d0.w, d0.z, 0x07060302u);
    H.u[2] = __builtin_amdgcn_perm(d1.y, d1.x, 0x07060302u);
    H.u[3] = __builtin_amdgcn_perm(d1.w, d1.z, 0x07060302u);
    L.u[0] = __builtin_amdgcn_perm(d0.y, d0.x, 0x05040100u);
    L.u[1] = __builtin_amdgcn_perm(d0.w, d0.z, 0x05040100u);
    L.u[2] = __builtin_amdgcn_perm(d1.y, d1.x, 0x05040100u);
    L.u[3] = __builtin_amdgcn_perm(d1.w, d1.z, 0x05040100u);
    ahi = H.s; alo = L.s;
}

// block = 1 wave (64 threads), 16 batch rows per wave; grid = B/16 = 256.
__global__ __launch_bounds__(64, 1)
void lstm2_mfma_kernel(const float* __restrict__ x,
                       const float* __restrict__ Wih0, const float* __restrict__ Whh0,
                       const float* __restrict__ bih0, const float* __restrict__ bhh0,
                       const float* __restrict__ Wih1, const float* __restrict__ Whh1,
                       const float* __restrict__ bih1, const float* __restrict__ bhh1,
                       const float* __restrict__ W1, const float* __restrict__ b1,
                       const float* __restrict__ W2, const float* __restrict__ b2,
                       float* __restrict__ out)
{
    __shared__ __align__(16) unsigned hbuf[2][16][HS];  // h as [bf16hi|bf16lo] dwords
    __shared__ __align__(16) unsigned xp[16][XS];       // x chunk, packed hi|lo
    __shared__ __align__(16) unsigned zp[8];            // zero pad for K-padding reads

    const int lane = threadIdx.x;
    const int q    = lane >> 4;          // quad 0..3
    const int n    = lane & 15;          // gate-col (B operand) / batch m (A operand)

    // ---- zero h state ----
    for (int i = lane; i < 2 * 16 * HS; i += 64) ((unsigned*)hbuf)[i] = 0u;
    if (lane < 8) zp[lane] = 0u;

    // ---- build persistent weight B-fragments: B[n=lane&15][k=q*8+e] ----
    // layer1 operand: k 0..15 = x feat, 16..47 = h1 unit, 48..63 = zero pad
    short8 b1h[8][2], b1l[8][2], b2h[8][2], b2l[8][2];
    #pragma unroll
    for (int c = 0; c < 8; ++c) {
        const int gate = c * 16 + n;
        #pragma unroll
        for (int f = 0; f < 2; ++f) {
            float w1v[8], w2v[8];
            #pragma unroll
            for (int e = 0; e < 8; ++e) {
                const int k = f * 32 + q * 8 + e;
                float wv;
                if (k < 16)       wv = Wih0[gate * 16 + k];
                else if (k < 48)  wv = Whh0[gate * 32 + (k - 16)];
                else              wv = 0.0f;
                w1v[e] = wv;
                // layer2 operand: k 0..31 = h1_t, 32..63 = h2_{t-1}
                w2v[e] = (k < 32) ? Wih1[gate * 32 + k] : Whh1[gate * 32 + (k - 32)];
            }
            split8(w1v, b1h[c][f], b1l[c][f]);
            split8(w2v, b2h[c][f], b2l[c][f]);
        }
    }
    float bs1[8], bs2[8];
    #pragma unroll
    for (int c = 0; c < 8; ++c) {
        const int gate = c * 16 + n;
        bs1[c] = bih0[gate] + bhh0[gate];
        bs2[c] = bih1[gate] + bhh1[gate];
    }

    float c1s[4][2], c2s[4][2];
    #pragma unroll
    for (int r = 0; r < 4; ++r) { c1s[r][0] = c1s[r][1] = 0.f; c2s[r][0] = c2s[r][1] = 0.f; }

    const float* xg = x + (size_t)blockIdx.x * 16 * (T_LEN * 16);

    #pragma unroll 1
    for (int t0 = 0; t0 < T_LEN; t0 += TC) {
        // ---- stage x chunk: 16 batch x 16 t x 16 feat, pack hi|lo into xp ----
        {
            const int bl = lane >> 2, f4 = lane & 3;    // batch row, feat quad
            #pragma unroll
            for (int it = 0; it < TC; ++it) {
                const float4 v = *(const float4*)(xg + (size_t)bl * (T_LEN * 16)
                                                     + (size_t)(t0 + it) * 16 + f4 * 4);
                uint4 pk;
                pk.x = pack_hilo(v.x); pk.y = pack_hilo(v.y);
                pk.z = pack_hilo(v.z); pk.w = pack_hilo(v.w);
                *(uint4*)&xp[bl][it * 16 + f4 * 4] = pk;
            }
        }
        __builtin_amdgcn_wave_barrier();

        #pragma unroll 1
        for (int tt = 0; tt < TC; ++tt) {
            // ---- layer1 A-frags: v = [x_t | h1_{t-1} | 0] ----
            const unsigned* p0 = (q < 2) ? &xp[n][tt * 16 + q * 8]
                                         : &hbuf[0][n][(q - 2) * 8];
            const unsigned* p1 = (q < 2) ? &hbuf[0][n][16 + q * 8] : zp;
            short8 a0h, a0l, a1h_, a1l_;
            frags_from_dwords(p0, a0h, a0l);
            frags_from_dwords(p1, a1h_, a1l_);

            // ---- gates1: 6 mfma per 16-gate chunk (3-term hi/lo) ----
            f32x4 g1[8];
            #pragma unroll
            for (int c = 0; c < 8; ++c) {
                f32x4 acc = {bs1[c], bs1[c], bs1[c], bs1[c]};
                acc = mfma16(a0h,  b1h[c][0], acc);
                acc = mfma16(a1h_, b1h[c][1], acc);
                acc = mfma16(a0l,  b1h[c][0], acc);
                acc = mfma16(a1l_, b1h[c][1], acc);
                acc = mfma16(a0h,  b1l[c][0], acc);
                acc = mfma16(a1h_, b1l[c][1], acc);
                g1[c] = acc;
            }
            // ---- act1: lane holds batches q*4+r, units {n, n+16} ----
            #pragma unroll
            for (int r = 0; r < 4; ++r) {
                #pragma unroll
                for (int jj = 0; jj < 2; ++jj) {
                    const float ig = fsig(g1[0 + jj][r]);
                    const float fg = fsig(g1[2 + jj][r]);
                    const float gg = ftanh(g1[4 + jj][r]);
                    const float og = fsig(g1[6 + jj][r]);
                    const float cc = fg * c1s[r][jj] + ig * gg;
                    c1s[r][jj] = cc;
                    const float h = og * ftanh(cc);
                    hbuf[0][q * 4 + r][n + 16 * jj] = pack_hilo(h);
                }
            }
            __builtin_amdgcn_wave_barrier();

            // ---- layer2 A-frags: u = [h1_t | h2_{t-1}] ----
            short8 u0h, u0l, u1h, u1l;
            frags_from_dwords(&hbuf[0][n][q * 8], u0h, u0l);
            frags_from_dwords(&hbuf[1][n][q * 8], u1h, u1l);

            f32x4 g2[8];
            #pragma unroll
            for (int c = 0; c < 8; ++c) {
                f32x4 acc = {bs2[c], bs2[c], bs2[c], bs2[c]};
                acc = mfma16(u0h, b2h[c][0], acc);
                acc = mfma16(u1h, b2h[c][1], acc);
                acc = mfma16(u0l, b2h[c][0], acc);
                acc = mfma16(u1l, b2h[c][1], acc);
                acc = mfma16(u0h, b2l[c][0], acc);
                acc = mfma16(u1h, b2l[c][1], acc);
                g2[c] = acc;
            }
            #pragma unroll
            for (int r = 0; r < 4; ++r) {
                #pragma unroll
                for (int jj = 0; jj < 2; ++jj) {
                    const float ig = fsig(g2[0 + jj][r]);
                    const float fg = fsig(g2[2 + jj][r]);
                    const float gg = ftanh(g2[4 + jj][r]);
                    const float og = fsig(g2[6 + jj][r]);
                    const float cc = fg * c2s[r][jj] + ig * gg;
                    c2s[r][jj] = cc;
                    const float h = og * ftanh(cc);
                    hbuf[1][q * 4 + r][n + 16 * jj] = pack_hilo(h);
                }
            }
            __builtin_amdgcn_wave_barrier();
        }
    }

    // ---- MLP head on h2_{T-1}: lane m < 16 handles batch m ----
    if (lane < 16) {
        float h2[32];
        #pragma unroll
        for (int k = 0; k < 32; ++k) {
            const unsigned d = hbuf[1][lane][k];
            h2[k] = __uint_as_float(d & 0xffff0000u) + __uint_as_float(d << 16);
        }
        float p = b2[0];
        #pragma unroll 1
        for (int jj = 0; jj < 16; ++jj) {
            float acc = b1[jj];
            #pragma unroll
            for (int k = 0; k < 32; ++k) acc += W1[jj * 32 + k] * h2[k];
            p += W2[jj] * fmaxf(acc, 0.f);
        }
        out[blockIdx.x * 16 + lane] = p;
    }
}

} // namespace

extern "C" void kernel_launch(void* const* d_in, const int* in_sizes, int n_in,
                              void* d_out, int out_size, void* d_ws, size_t ws_size,
                              hipStream_t stream) {
    const float* x    = (const float*)d_in[0];
    const float* Wih0 = (const float*)d_in[1];
    const float* Whh0 = (const float*)d_in[2];
    const float* bih0 = (const float*)d_in[3];
    const float* bhh0 = (const float*)d_in[4];
    const float* Wih1 = (const float*)d_in[5];
    const float* Whh1 = (const float*)d_in[6];
    const float* bih1 = (const float*)d_in[7];
    const float* bhh1 = (const float*)d_in[8];
    const float* W1   = (const float*)d_in[9];
    const float* b1   = (const float*)d_in[10];
    const float* W2   = (const float*)d_in[11];
    const float* b2   = (const float*)d_in[12];

    const int batch  = out_size;            // 4096
    const int blocks = batch / 16;          // 256 single-wave blocks

    hipLaunchKernelGGL(lstm2_mfma_kernel, dim3(blocks), dim3(64), 0, stream,
                       x, Wih0, Whh0, bih0, bhh0, Wih1, Whh1, bih1, bhh1,
                       W1, b1, W2, b2, (float*)d_out);
}

// Round 5
// 779.968 us; speedup vs baseline: 2.9560x; 1.7583x over previous
//
#include <hip/hip_runtime.h>

namespace {

typedef __attribute__((ext_vector_type(8))) short short8;   // 8 bf16 (4 VGPRs)
typedef __attribute__((ext_vector_type(4))) float f32x4;

constexpr int T_LEN = 512;
constexpr int TC    = 16;    // timesteps per x-staging chunk
constexpr int HSTR  = 40;    // h-plane row stride (shorts): 32 used + 8 pad, 80B (16B-mult)
constexpr int XSTR  = 264;   // x-plane row stride (shorts): 256 used + 8 pad, 528B (16B-mult)

__device__ __forceinline__ float fsig(float x) {
    return __builtin_amdgcn_rcpf(1.0f + __expf(-x));
}
__device__ __forceinline__ float ftanh(float x) {
    return 2.0f * __builtin_amdgcn_rcpf(1.0f + __expf(-2.0f * x)) - 1.0f;
}
__device__ __forceinline__ f32x4 mfma16(short8 a, short8 b, f32x4 c) {
    return __builtin_amdgcn_mfma_f32_16x16x32_bf16(a, b, c, 0, 0, 0);
}
// pack bf16-truncations of (a,b) into one dword, b in LOW short
__device__ __forceinline__ unsigned permhi(float a, float b) {
    return __builtin_amdgcn_perm(__float_as_uint(a), __float_as_uint(b), 0x07060302u);
}
__device__ __forceinline__ float lo_resid(float v) {
    return v - __uint_as_float(__float_as_uint(v) & 0xffff0000u);
}

// block = 128 threads = 2 waves over the SAME 16 batch rows.
// wave 0 = layer-1 stage (step t), wave 1 = layer-2 stage (step t-1) + MLP head.
// h1 handed via 2-slot LDS ring of bf16 hi/lo planes; one barrier per step.
__global__ __launch_bounds__(128)
void lstm2_pipe_kernel(const float* __restrict__ x,
                       const float* __restrict__ Wih0, const float* __restrict__ Whh0,
                       const float* __restrict__ bih0, const float* __restrict__ bhh0,
                       const float* __restrict__ Wih1, const float* __restrict__ Whh1,
                       const float* __restrict__ bih1, const float* __restrict__ bhh1,
                       const float* __restrict__ W1, const float* __restrict__ b1,
                       const float* __restrict__ W2, const float* __restrict__ b2,
                       float* __restrict__ out)
{
    __shared__ __align__(16) short sh1hi[2][16 * HSTR], sh1lo[2][16 * HSTR]; // h1 ring
    __shared__ __align__(16) short sh2hi[16 * HSTR],    sh2lo[16 * HSTR];    // h2 planes
    __shared__ __align__(16) short sxhi[16 * XSTR],     sxlo[16 * XSTR];     // x chunk
    __shared__ __align__(16) unsigned szero[8];                              // zero pad

    const int tid  = threadIdx.x;
    const int wid  = tid >> 6;           // 0 = layer1 wave, 1 = layer2 wave
    const int lane = tid & 63;
    const int q    = lane >> 4;          // quad
    const int n    = lane & 15;          // MFMA col (B) / batch row (A)

    // ---- zero h planes ----
    for (int i = tid; i < 16 * HSTR; i += 128) {
        sh1hi[0][i] = 0; sh1hi[1][i] = 0; sh1lo[0][i] = 0; sh1lo[1][i] = 0;
        sh2hi[i] = 0;    sh2lo[i] = 0;
    }
    if (tid < 8) szero[tid] = 0u;

    // ---- per-wave persistent weight B-fragments + bias C-operands ----
    // chunk c = gate*2 + p ; lane-col n <-> unit (2n+p) of that gate.
    // L1 K-map: k 0..31 = h1_{t-1}, 32..47 = x_t, 48..63 = 0
    // L2 K-map: k 0..31 = h1_t,     32..63 = h2_{t-1}
    short8 bh[8][2], bl[8][2];
    f32x4  bsp[8];
    const bool isL1 = (wid == 0);
    #pragma unroll
    for (int c = 0; c < 8; ++c) {
        const int gate = c >> 1, p = c & 1;
        const int row  = gate * 32 + 2 * n + p;
        #pragma unroll
        for (int f = 0; f < 2; ++f) {
            #pragma unroll
            for (int e = 0; e < 8; ++e) {
                const int kk = f * 32 + q * 8 + e;
                float v;
                if (isL1) v = (kk < 32) ? Whh0[row * 32 + kk]
                            : (kk < 48) ? Wih0[row * 16 + (kk - 32)] : 0.0f;
                else      v = (kk < 32) ? Wih1[row * 32 + kk]
                                        : Whh1[row * 32 + (kk - 32)];
                const unsigned b = __float_as_uint(v);
                bh[c][f][e] = (short)(b >> 16);
                const float hif = __uint_as_float(b & 0xffff0000u);
                bl[c][f][e] = (short)(__float_as_uint(v - hif) >> 16);
            }
        }
        const float bv = isL1 ? (bih0[row] + bhh0[row]) : (bih1[row] + bhh1[row]);
        bsp[c] = (f32x4){bv, bv, bv, bv};
    }

    float cst[4][2];                    // c-state: [r][p] (c1 for wave0, c2 for wave1)
    #pragma unroll
    for (int r = 0; r < 4; ++r) { cst[r][0] = 0.f; cst[r][1] = 0.f; }

    const float4* xg = (const float4*)x + (size_t)blockIdx.x * 16 * (T_LEN * 4);

    #pragma unroll 1
    for (int i = 0; i <= T_LEN; ++i) {
        if (i < T_LEN && (i & (TC - 1)) == 0) {
            __syncthreads();            // prior chunk's reads (iter i-1) are done
            // stage x[t0 = i .. i+15] into hi/lo planes (both waves help)
            const int b = tid & 15, w = tid >> 4;     // batch row, 8 threads/row
            const float4* src = xg + (size_t)b * (T_LEN * 4) + (size_t)i * 4;
            short* dh = &sxhi[b * XSTR];
            short* dl = &sxlo[b * XSTR];
            #pragma unroll
            for (int ii = 0; ii < 8; ++ii) {
                const int el = w + ii * 8;            // float4 index within chunk row
                const float4 v = src[el];
                uint2 hp, lp;
                hp.x = permhi(v.y, v.x);
                hp.y = permhi(v.w, v.z);
                lp.x = permhi(lo_resid(v.y), lo_resid(v.x));
                lp.y = permhi(lo_resid(v.w), lo_resid(v.z));
                *(uint2*)&dh[el * 4] = hp;
                *(uint2*)&dl[el * 4] = lp;
            }
        }
        __syncthreads();

        if (wid == 0) {
            if (i < T_LEN) {
                const int t = i, tt = t & (TC - 1);
                const int ps = (t + 1) & 1;           // prev slot (t-1)&1
                const int cs = t & 1;                 // current slot
                // A-frags: frag0 = h1_{t-1}, frag1 = [x_t | zeros]
                short8 a0h = *(const short8*)&sh1hi[ps][n * HSTR + q * 8];
                short8 a0l = *(const short8*)&sh1lo[ps][n * HSTR + q * 8];
                const short* ph = (q < 2) ? &sxhi[n * XSTR + tt * 16 + q * 8]
                                          : (const short*)szero;
                const short* pl = (q < 2) ? &sxlo[n * XSTR + tt * 16 + q * 8]
                                          : (const short*)szero;
                short8 a1h = *(const short8*)ph;
                short8 a1l = *(const short8*)pl;

                f32x4 g[8];
                #pragma unroll
                for (int c = 0; c < 8; ++c) {
                    f32x4 acc = mfma16(a0h, bh[c][0], bsp[c]);
                    acc = mfma16(a1h, bh[c][1], acc);
                    acc = mfma16(a0l, bh[c][0], acc);
                    acc = mfma16(a1l, bh[c][1], acc);
                    acc = mfma16(a0h, bl[c][0], acc);
                    acc = mfma16(a1h, bl[c][1], acc);
                    g[c] = acc;
                }
                #pragma unroll
                for (int r = 0; r < 4; ++r) {
                    float hv[2];
                    #pragma unroll
                    for (int p = 0; p < 2; ++p) {
                        const float ig = fsig(g[0 + p][r]);
                        const float fg = fsig(g[2 + p][r]);
                        const float gg = ftanh(g[4 + p][r]);
                        const float og = fsig(g[6 + p][r]);
                        const float cc = fg * cst[r][p] + ig * gg;
                        cst[r][p] = cc;
                        hv[p] = og * ftanh(cc);
                    }
                    const int ro = (q * 4 + r) * HSTR + 2 * n;
                    *(unsigned*)&sh1hi[cs][ro] = permhi(hv[1], hv[0]);
                    *(unsigned*)&sh1lo[cs][ro] = permhi(lo_resid(hv[1]), lo_resid(hv[0]));
                }
            }
        } else {
            if (i >= 1) {
                const int t = i - 1;
                const int cs = t & 1;                 // slot holding h1_t
                // A-frags: frag0 = h1_t, frag1 = h2_{t-1}
                short8 a0h = *(const short8*)&sh1hi[cs][n * HSTR + q * 8];
                short8 a0l = *(const short8*)&sh1lo[cs][n * HSTR + q * 8];
                short8 a1h = *(const short8*)&sh2hi[n * HSTR + q * 8];
                short8 a1l = *(const short8*)&sh2lo[n * HSTR + q * 8];

                f32x4 g[8];
                #pragma unroll
                for (int c = 0; c < 8; ++c) {
                    f32x4 acc = mfma16(a0h, bh[c][0], bsp[c]);
                    acc = mfma16(a1h, bh[c][1], acc);
                    acc = mfma16(a0l, bh[c][0], acc);
                    acc = mfma16(a1l, bh[c][1], acc);
                    acc = mfma16(a0h, bl[c][0], acc);
                    acc = mfma16(a1h, bl[c][1], acc);
                    g[c] = acc;
                }
                #pragma unroll
                for (int r = 0; r < 4; ++r) {
                    float hv[2];
                    #pragma unroll
                    for (int p = 0; p < 2; ++p) {
                        const float ig = fsig(g[0 + p][r]);
                        const float fg = fsig(g[2 + p][r]);
                        const float gg = ftanh(g[4 + p][r]);
                        const float og = fsig(g[6 + p][r]);
                        const float cc = fg * cst[r][p] + ig * gg;
                        cst[r][p] = cc;
                        hv[p] = og * ftanh(cc);
                    }
                    const int ro = (q * 4 + r) * HSTR + 2 * n;
                    *(unsigned*)&sh2hi[ro] = permhi(hv[1], hv[0]);
                    *(unsigned*)&sh2lo[ro] = permhi(lo_resid(hv[1]), lo_resid(hv[0]));
                }
            }
        }
    }

    // ---- MLP head on h2_{T-1} (wave1 wrote it; same-wave in-order LDS) ----
    if (wid == 1 && lane < 16) {
        float h2v[32];
        #pragma unroll
        for (int kk = 0; kk < 32; ++kk) {
            h2v[kk] = __uint_as_float(((unsigned)(unsigned short)sh2hi[lane * HSTR + kk]) << 16)
                    + __uint_as_float(((unsigned)(unsigned short)sh2lo[lane * HSTR + kk]) << 16);
        }
        float pacc = b2[0];
        #pragma unroll 1
        for (int jj = 0; jj < 16; ++jj) {
            float acc = b1[jj];
            #pragma unroll
            for (int kk = 0; kk < 32; ++kk) acc += W1[jj * 32 + kk] * h2v[kk];
            pacc += W2[jj] * fmaxf(acc, 0.f);
        }
        out[blockIdx.x * 16 + lane] = pacc;
    }
}

} // namespace

extern "C" void kernel_launch(void* const* d_in, const int* in_sizes, int n_in,
                              void* d_out, int out_size, void* d_ws, size_t ws_size,
                              hipStream_t stream) {
    const float* x    = (const float*)d_in[0];
    const float* Wih0 = (const float*)d_in[1];
    const float* Whh0 = (const float*)d_in[2];
    const float* bih0 = (const float*)d_in[3];
    const float* bhh0 = (const float*)d_in[4];
    const float* Wih1 = (const float*)d_in[5];
    const float* Whh1 = (const float*)d_in[6];
    const float* bih1 = (const float*)d_in[7];
    const float* bhh1 = (const float*)d_in[8];
    const float* W1   = (const float*)d_in[9];
    const float* b1   = (const float*)d_in[10];
    const float* W2   = (const float*)d_in[11];
    const float* b2   = (const float*)d_in[12];

    const int batch  = out_size;            // 4096
    const int blocks = batch / 16;          // 256 blocks x 2 waves

    hipLaunchKernelGGL(lstm2_pipe_kernel, dim3(blocks), dim3(128), 0, stream,
                       x, Wih0, Whh0, bih0, bhh0, Wih1, Whh1, bih1, bhh1,
                       W1, b1, W2, b2, (float*)d_out);
}